// Round 2
// baseline (551.025 us; speedup 1.0000x reference)
//
#include <hip/hip_runtime.h>
#include <stdint.h>

typedef __bf16 bf16x8 __attribute__((ext_vector_type(8)));
typedef float floatx4 __attribute__((ext_vector_type(4)));

#define LDP 136  // LDS row stride in bf16 elems: 272 B = 16B-aligned, 2-way bank alias (free)

__device__ __forceinline__ float bf2f(unsigned short u) {
  return __uint_as_float(((unsigned)u) << 16);
}
__device__ __forceinline__ unsigned short f2bf(float f) {
  unsigned x = __float_as_uint(f);
  unsigned r = (x + 0x7fffu + ((x >> 16) & 1u)) >> 16;  // RNE
  return (unsigned short)r;
}

// ---------------- K1a: fp32 -> bf16 convert of node embeddings ----------------
__global__ __launch_bounds__(256) void k_convert_emb(
    const float* __restrict__ src, unsigned short* __restrict__ dst, int n4) {
  int i = blockIdx.x * 256 + threadIdx.x;
  if (i >= n4) return;
  float4 v = ((const float4*)src)[i];
  ushort4 o;
  o.x = f2bf(v.x); o.y = f2bf(v.y); o.z = f2bf(v.z); o.w = f2bf(v.w);
  ((ushort4*)dst)[i] = o;
}

// ---------------- K1b: build transposed bf16 weight tables ----------------
// WcatT[j][k], j in 0..511, k in 0..127:
//   j<128:   W1[k][j]          (src-half of W1)
//   j<256:   A1[k][j-128]      (src-half of A1)
//   j<384:   W1[128+k][j-256]  (tgt-half of W1)
//   else:    A1[128+k][j-384]  (tgt-half of A1)
// A2T[n][k] = A2[k][n]  (n in 0..63, k in 0..127)
__global__ __launch_bounds__(256) void k_prep_weights(
    const float* __restrict__ W1, const float* __restrict__ A1,
    const float* __restrict__ A2,
    unsigned short* __restrict__ WcatT, unsigned short* __restrict__ A2T) {
  int idx = blockIdx.x * 256 + threadIdx.x;
  if (idx < 512 * 128) {
    int j = idx >> 7, k = idx & 127;
    float v;
    if (j < 128)      v = W1[k * 128 + j];
    else if (j < 256) v = A1[k * 128 + (j - 128)];
    else if (j < 384) v = W1[(128 + k) * 128 + (j - 256)];
    else              v = A1[(128 + k) * 128 + (j - 384)];
    WcatT[idx] = f2bf(v);
  } else if (idx < 512 * 128 + 64 * 128) {
    int i = idx - 512 * 128;
    int n = i >> 7, k = i & 127;
    A2T[i] = f2bf(A2[k * 64 + n]);
  }
}

// ---------------- K2: per-node precompute GEMM  P = emb @ Wcat ----------------
// M=N_nodes, K=128, N=512. Block: 256 thr, tile 64 rows x 128 cols.
__global__ __launch_bounds__(256, 3) void k_precompute(
    const unsigned short* __restrict__ emb,    // N x 128 bf16
    const unsigned short* __restrict__ WcatT,  // 512 x 128 bf16 (transposed)
    unsigned short* __restrict__ P,            // N x 512 bf16
    int N) {
  __shared__ __align__(16) unsigned short a_lds[64 * LDP];
  __shared__ __align__(16) unsigned short b_lds[128 * LDP];
  const int t = threadIdx.x;
  const int m0 = (blockIdx.x >> 2) * 64;
  const int j0 = (blockIdx.x & 3) * 128;

  // stage A tile (64 x 128 bf16)
  for (int it = 0; it < 4; ++it) {
    int i = it * 256 + t;
    int row = i >> 4, c8 = (i & 15) * 8;
    uint4 v = make_uint4(0u, 0u, 0u, 0u);
    if (m0 + row < N) v = *(const uint4*)(emb + (size_t)(m0 + row) * 128 + c8);
    *(uint4*)&a_lds[row * LDP + c8] = v;
  }
  // stage Bt tile (128 cols x 128 k, already transposed in global)
  for (int it = 0; it < 8; ++it) {
    int i = it * 256 + t;
    int jr = i >> 4, c8 = (i & 15) * 8;
    uint4 v = *(const uint4*)(WcatT + (size_t)(j0 + jr) * 128 + c8);
    *(uint4*)&b_lds[jr * LDP + c8] = v;
  }
  __syncthreads();

  const int w = t >> 6, l = t & 63;
  const int lr = l & 15, quad = l >> 4;
  floatx4 acc[8];
  for (int nt = 0; nt < 8; ++nt) acc[nt] = (floatx4){0.f, 0.f, 0.f, 0.f};
  for (int ks = 0; ks < 4; ++ks) {
    bf16x8 af = *(const bf16x8*)&a_lds[(w * 16 + lr) * LDP + ks * 32 + quad * 8];
    for (int nt = 0; nt < 8; ++nt) {
      bf16x8 bfv = *(const bf16x8*)&b_lds[(nt * 16 + lr) * LDP + ks * 32 + quad * 8];
      acc[nt] = __builtin_amdgcn_mfma_f32_16x16x32_bf16(af, bfv, acc[nt], 0, 0, 0);
    }
  }
  for (int nt = 0; nt < 8; ++nt) {
    int col = j0 + nt * 16 + lr;
    for (int r = 0; r < 4; ++r) {
      int n = m0 + w * 16 + quad * 4 + r;
      if (n < N) P[(size_t)n * 512 + col] = f2bf(acc[nt][r]);
    }
  }
}

// ---------------- K3: per-edge gather + heads ----------------
// Block: 256 thr = 4 waves, 64 edges/block. Outputs are FLOAT32.
__global__ __launch_bounds__(256, 4) void k_edges(
    const unsigned short* __restrict__ P,     // N x 512 bf16
    const unsigned short* __restrict__ A2Tg,  // 64 x 128 bf16
    const int* __restrict__ edges,            // E x 2
    const int* __restrict__ army,             // N
    const float* __restrict__ b1, const float* __restrict__ ab1,
    const float* __restrict__ W2, const float* __restrict__ b2,
    const float* __restrict__ ab2,
    float* __restrict__ out_edge,             // E  (fp32)
    float* __restrict__ out_army,             // E x 64 (fp32)
    int E) {
  __shared__ __align__(16) unsigned short ha[64 * LDP];
  __shared__ __align__(16) unsigned short a2t[64 * LDP];
  __shared__ float s_b1cat[256];
  __shared__ float s_w2[128];
  __shared__ float s_ab2[64];
  __shared__ int s_army[64];
  __shared__ int s_edges[128];

  const int t = threadIdx.x;
  const int e0 = blockIdx.x * 64;

  // phase 0: stage A2^T tile + small params
  for (int it = 0; it < 4; ++it) {
    int i = it * 256 + t;
    int n = i >> 4, c8 = (i & 15) * 8;
    *(uint4*)&a2t[n * LDP + c8] = *(const uint4*)(A2Tg + n * 128 + c8);
  }
  s_b1cat[t] = (t < 128) ? b1[t] : ab1[t - 128];
  if (t < 128) {
    s_w2[t] = W2[t];
    int ei = e0 * 2 + t;
    s_edges[t] = (ei < E * 2) ? edges[ei] : 0;
  }
  if (t < 64) s_ab2[t] = ab2[t];
  __syncthreads();

  // phase 1: gather P rows, build h (relu), edge logit, stage ha into LDS
  const float b2v = b2[0];
  const int lp = t & 31;   // 32 threads per edge
  const int eh = t >> 5;   // 8 edges per iteration
  const int j0 = lp * 8;   // j0 in 0..248
  for (int it = 0; it < 8; ++it) {
    int el = it * 8 + eh;
    if (e0 + el >= E) continue;
    int src = s_edges[el * 2];
    int tgt = s_edges[el * 2 + 1];
    union { uint4 u; unsigned short s[8]; } vs, vt;
    vs.u = *(const uint4*)(P + (size_t)src * 512 + j0);
    vt.u = *(const uint4*)(P + (size_t)tgt * 512 + 256 + j0);
    float h[8];
#pragma unroll
    for (int i = 0; i < 8; ++i) {
      float x = bf2f(vs.s[i]) + bf2f(vt.s[i]) + s_b1cat[j0 + i];
      h[i] = x > 0.f ? x : 0.f;
    }
    if (lp < 16) {  // j in 0..127: W2 head
      float part = 0.f;
#pragma unroll
      for (int i = 0; i < 8; ++i) part += h[i] * s_w2[j0 + i];
      part += __shfl_down(part, 8, 16);
      part += __shfl_down(part, 4, 16);
      part += __shfl_down(part, 2, 16);
      part += __shfl_down(part, 1, 16);
      if (lp == 0) {
        int sa = army[src], ta = army[tgt];
        float logit = part + b2v;
        if (sa <= 2 || ta >= 3 * sa) logit -= 1.f;
        if (src == tgt) logit -= 100.f;
        out_edge[e0 + el] = logit;
        s_army[el] = sa;
      }
    } else {  // j in 128..255: army head input -> LDS (bf16)
      union { uint4 u; unsigned short s[8]; } ov;
#pragma unroll
      for (int i = 0; i < 8; ++i) ov.s[i] = f2bf(h[i]);
      *(uint4*)&ha[el * LDP + (j0 - 128)] = ov.u;
    }
  }
  __syncthreads();

  // phase 2: army logits via MFMA. Wave w: edges w*16..w*16+15; 16x128 @ 128x64.
  const int w = t >> 6, l = t & 63;
  const int lr = l & 15, quad = l >> 4;
  floatx4 acc[4];
  for (int nt = 0; nt < 4; ++nt) acc[nt] = (floatx4){0.f, 0.f, 0.f, 0.f};
  for (int ks = 0; ks < 4; ++ks) {
    bf16x8 af = *(const bf16x8*)&ha[(w * 16 + lr) * LDP + ks * 32 + quad * 8];
#pragma unroll
    for (int nt = 0; nt < 4; ++nt) {
      bf16x8 bfv = *(const bf16x8*)&a2t[(nt * 16 + lr) * LDP + ks * 32 + quad * 8];
      acc[nt] = __builtin_amdgcn_mfma_f32_16x16x32_bf16(af, bfv, acc[nt], 0, 0, 0);
    }
  }
#pragma unroll
  for (int nt = 0; nt < 4; ++nt) {
    int col = nt * 16 + lr;
    float bias = s_ab2[col];
#pragma unroll
    for (int r = 0; r < 4; ++r) {
      int el = w * 16 + quad * 4 + r;
      if (e0 + el >= E) continue;
      int sa = s_army[el];
      float v = acc[nt][r] + bias;
      v = (col < sa) ? v : -1e9f;  // col <= max_sendable = sa-1
      out_army[(size_t)(e0 + el) * 64 + col] = v;
    }
  }
}

extern "C" void kernel_launch(void* const* d_in, const int* in_sizes, int n_in,
                              void* d_out, int out_size, void* d_ws, size_t ws_size,
                              hipStream_t stream) {
  const float* emb_f = (const float*)d_in[0];
  const int* edges   = (const int*)d_in[1];
  const int* army    = (const int*)d_in[2];
  const float* W1    = (const float*)d_in[3];
  const float* b1    = (const float*)d_in[4];
  const float* W2    = (const float*)d_in[5];
  const float* b2    = (const float*)d_in[6];
  const float* A1    = (const float*)d_in[7];
  const float* ab1   = (const float*)d_in[8];
  const float* A2    = (const float*)d_in[9];
  const float* ab2   = (const float*)d_in[10];

  const int N = in_sizes[0] / 128;  // 100000 nodes
  const int E = in_sizes[1] / 2;    // 1000000 edges

  // workspace layout (all 16B-aligned)
  char* ws = (char*)d_ws;
  unsigned short* emb_bf = (unsigned short*)ws;                       // N*128 bf16
  unsigned short* WcatT  = (unsigned short*)(ws + (size_t)N * 256);   // 512*128 bf16
  unsigned short* A2T    = WcatT + 512 * 128;                         // 64*128 bf16
  unsigned short* P      = A2T + 64 * 128;                            // N*512 bf16

  float* out_edge = (float*)d_out;  // fp32 outputs (reference dtype)
  float* out_army = out_edge + E;

  int n4 = (N * 128) / 4;
  hipLaunchKernelGGL(k_convert_emb, dim3((n4 + 255) / 256), dim3(256), 0, stream,
                     emb_f, emb_bf, n4);
  hipLaunchKernelGGL(k_prep_weights, dim3((512 * 128 + 64 * 128 + 255) / 256), dim3(256),
                     0, stream, W1, A1, A2, WcatT, A2T);
  hipLaunchKernelGGL(k_precompute, dim3(((N + 63) / 64) * 4), dim3(256), 0, stream,
                     emb_bf, WcatT, P, N);
  hipLaunchKernelGGL(k_edges, dim3((E + 63) / 64), dim3(256), 0, stream,
                     P, A2T, edges, army, b1, ab1, W2, b2, ab2,
                     out_edge, out_army, E);
}

// Round 3
// 459.646 us; speedup vs baseline: 1.1988x; 1.1988x over previous
//
#include <hip/hip_runtime.h>
#include <stdint.h>

typedef __bf16 bf16x8 __attribute__((ext_vector_type(8)));
typedef float floatx4 __attribute__((ext_vector_type(4)));
typedef float floatx2 __attribute__((ext_vector_type(2)));

#define LDP 136    // bf16 LDS row stride in elems (272 B; 2-way bank alias = free)
#define LDP8 136   // fp8 LDS row stride in BYTES (8B-aligned rows)

__device__ __forceinline__ float bf2f(unsigned short u) {
  return __uint_as_float(((unsigned)u) << 16);
}
__device__ __forceinline__ unsigned short f2bf(float f) {
  unsigned x = __float_as_uint(f);
  unsigned r = (x + 0x7fffu + ((x >> 16) & 1u)) >> 16;  // RNE
  return (unsigned short)r;
}
__device__ __forceinline__ unsigned char f2fp8(float x) {
  int p = __builtin_amdgcn_cvt_pk_fp8_f32(x, 0.f, 0, false);
  return (unsigned char)(p & 0xff);
}

union LLU { uint2 u2; long long ll; };

// ---------------- K1a: fp32 -> bf16 convert of node embeddings ----------------
__global__ __launch_bounds__(256) void k_convert_emb(
    const float* __restrict__ src, unsigned short* __restrict__ dst, int n4) {
  int i = blockIdx.x * 256 + threadIdx.x;
  if (i >= n4) return;
  float4 v = ((const float4*)src)[i];
  ushort4 o;
  o.x = f2bf(v.x); o.y = f2bf(v.y); o.z = f2bf(v.z); o.w = f2bf(v.w);
  ((ushort4*)dst)[i] = o;
}

// ---------------- K1b: transposed weight tables ----------------
// WcatT (bf16) [j][k], j 0..511:  j<128: W1[k][j] ; j<256: A1[k][j-128] ;
//   j<384: W1[128+k][j-256] ; else A1[128+k][j-384]
// A2T8 (fp8)  [n][k] = fp8(A2[k][n]), n 0..63, k 0..127
__global__ __launch_bounds__(256) void k_prep_weights(
    const float* __restrict__ W1, const float* __restrict__ A1,
    const float* __restrict__ A2,
    unsigned short* __restrict__ WcatT, unsigned char* __restrict__ A2T8) {
  int idx = blockIdx.x * 256 + threadIdx.x;
  if (idx < 512 * 128) {
    int j = idx >> 7, k = idx & 127;
    float v;
    if (j < 128)      v = W1[k * 128 + j];
    else if (j < 256) v = A1[k * 128 + (j - 128)];
    else if (j < 384) v = W1[(128 + k) * 128 + (j - 256)];
    else              v = A1[(128 + k) * 128 + (j - 384)];
    WcatT[idx] = f2bf(v);
  } else if (idx < 512 * 128 + 64 * 128) {
    int i = idx - 512 * 128;
    int n = i >> 7, k = i & 127;
    A2T8[i] = f2fp8(A2[k * 64 + n]);
  }
}

// ---------------- K2: P = emb @ Wcat  (bf16 MFMA, fp8 output) ----------------
__global__ __launch_bounds__(256, 3) void k_precompute(
    const unsigned short* __restrict__ emb,    // N x 128 bf16
    const unsigned short* __restrict__ WcatT,  // 512 x 128 bf16 (transposed)
    unsigned char* __restrict__ P8,            // N x 512 fp8
    int N) {
  __shared__ __align__(16) unsigned short a_lds[64 * LDP];
  __shared__ __align__(16) unsigned short b_lds[128 * LDP];
  const int t = threadIdx.x;
  const int m0 = (blockIdx.x >> 2) * 64;
  const int j0 = (blockIdx.x & 3) * 128;

  for (int it = 0; it < 4; ++it) {
    int i = it * 256 + t;
    int row = i >> 4, c8 = (i & 15) * 8;
    uint4 v = make_uint4(0u, 0u, 0u, 0u);
    if (m0 + row < N) v = *(const uint4*)(emb + (size_t)(m0 + row) * 128 + c8);
    *(uint4*)&a_lds[row * LDP + c8] = v;
  }
  for (int it = 0; it < 8; ++it) {
    int i = it * 256 + t;
    int jr = i >> 4, c8 = (i & 15) * 8;
    uint4 v = *(const uint4*)(WcatT + (size_t)(j0 + jr) * 128 + c8);
    *(uint4*)&b_lds[jr * LDP + c8] = v;
  }
  __syncthreads();

  const int w = t >> 6, l = t & 63;
  const int lr = l & 15, quad = l >> 4;
  floatx4 acc[8];
  for (int nt = 0; nt < 8; ++nt) acc[nt] = (floatx4){0.f, 0.f, 0.f, 0.f};
  for (int ks = 0; ks < 4; ++ks) {
    bf16x8 af = *(const bf16x8*)&a_lds[(w * 16 + lr) * LDP + ks * 32 + quad * 8];
    for (int nt = 0; nt < 8; ++nt) {
      bf16x8 bfv = *(const bf16x8*)&b_lds[(nt * 16 + lr) * LDP + ks * 32 + quad * 8];
      acc[nt] = __builtin_amdgcn_mfma_f32_16x16x32_bf16(af, bfv, acc[nt], 0, 0, 0);
    }
  }
  for (int nt = 0; nt < 8; ++nt) {
    int col = j0 + nt * 16 + lr;
    for (int r = 0; r < 4; ++r) {
      int n = m0 + w * 16 + quad * 4 + r;
      if (n < N) P8[(size_t)n * 512 + col] = f2fp8(acc[nt][r]);
    }
  }
}

// ---------------- K3: per-edge gather + heads (fp8 P table) ----------------
// 256 thr = 4 waves, 64 edges/block.
__global__ __launch_bounds__(256, 6) void k_edges(
    const unsigned char* __restrict__ P8,     // N x 512 fp8
    const unsigned char* __restrict__ A2T8g,  // 64 x 128 fp8
    const int* __restrict__ edges,            // E x 2
    const int* __restrict__ army,             // N
    const float* __restrict__ b1, const float* __restrict__ ab1,
    const float* __restrict__ W2, const float* __restrict__ b2,
    const float* __restrict__ ab2,
    float* __restrict__ out_edge,             // E (fp32)
    float* __restrict__ out_army,             // E x 64 (fp32)
    int E) {
  __shared__ __align__(16) unsigned char ha8[64 * LDP8];
  __shared__ __align__(16) unsigned char a2t8[64 * LDP8];
  __shared__ float s_b1cat[256];
  __shared__ float s_w2[128];
  __shared__ float s_ab2[64];
  __shared__ int s_army[64];
  __shared__ int s_edges[128];

  const int t = threadIdx.x;
  const int e0 = blockIdx.x * 64;

  // phase 0: stage A2T (8 KB) + small params
  for (int it = 0; it < 2; ++it) {
    int i = it * 256 + t;
    int n = i >> 3, c = (i & 7) * 16;
    *(uint4*)&a2t8[n * LDP8 + c] = *(const uint4*)(A2T8g + n * 128 + c);
  }
  s_b1cat[t] = (t < 128) ? b1[t] : ab1[t - 128];
  if (t < 128) {
    s_w2[t] = W2[t];
    int ei = e0 * 2 + t;
    s_edges[t] = (ei < E * 2) ? edges[ei] : 0;
  }
  if (t < 64) s_ab2[t] = ab2[t];
  __syncthreads();

  // phase 1: gather fp8 P rows, h = relu(ps+pt+b), edge logit, ha8 -> LDS
  const float b2v = b2[0];
  const int lp = t & 31;   // 32 threads per edge
  const int eh = t >> 5;   // 8 edges per pass
  const int j0 = lp * 8;   // dims j0..j0+7
  // hoist loop-invariant per-lane params out of the 8-iteration loop
  float rb[8], rw[8];
#pragma unroll
  for (int i = 0; i < 8; ++i) rb[i] = s_b1cat[j0 + i];
  if (lp < 16) {
#pragma unroll
    for (int i = 0; i < 8; ++i) rw[i] = s_w2[j0 + i];
  }
  for (int it = 0; it < 8; ++it) {
    int el = it * 8 + eh;
    if (e0 + el >= E) continue;
    int src = s_edges[el * 2];
    int tgt = s_edges[el * 2 + 1];
    uint2 us = *(const uint2*)(P8 + (size_t)src * 512 + j0);
    uint2 ut = *(const uint2*)(P8 + (size_t)tgt * 512 + 256 + j0);
    floatx2 s01 = __builtin_amdgcn_cvt_pk_f32_fp8(us.x, false);
    floatx2 s23 = __builtin_amdgcn_cvt_pk_f32_fp8(us.x, true);
    floatx2 s45 = __builtin_amdgcn_cvt_pk_f32_fp8(us.y, false);
    floatx2 s67 = __builtin_amdgcn_cvt_pk_f32_fp8(us.y, true);
    floatx2 t01 = __builtin_amdgcn_cvt_pk_f32_fp8(ut.x, false);
    floatx2 t23 = __builtin_amdgcn_cvt_pk_f32_fp8(ut.x, true);
    floatx2 t45 = __builtin_amdgcn_cvt_pk_f32_fp8(ut.y, false);
    floatx2 t67 = __builtin_amdgcn_cvt_pk_f32_fp8(ut.y, true);
    float h[8];
    h[0] = s01.x + t01.x + rb[0]; h[1] = s01.y + t01.y + rb[1];
    h[2] = s23.x + t23.x + rb[2]; h[3] = s23.y + t23.y + rb[3];
    h[4] = s45.x + t45.x + rb[4]; h[5] = s45.y + t45.y + rb[5];
    h[6] = s67.x + t67.x + rb[6]; h[7] = s67.y + t67.y + rb[7];
#pragma unroll
    for (int i = 0; i < 8; ++i) h[i] = h[i] > 0.f ? h[i] : 0.f;
    if (lp < 16) {  // dims 0..127: W2 head
      float part = 0.f;
#pragma unroll
      for (int i = 0; i < 8; ++i) part += h[i] * rw[i];
      part += __shfl_down(part, 8, 16);
      part += __shfl_down(part, 4, 16);
      part += __shfl_down(part, 2, 16);
      part += __shfl_down(part, 1, 16);
      if (lp == 0) {
        int sa = army[src], ta = army[tgt];
        float logit = part + b2v;
        if (sa <= 2 || ta >= 3 * sa) logit -= 1.f;
        if (src == tgt) logit -= 100.f;
        out_edge[e0 + el] = logit;
        s_army[el] = sa;
      }
    } else {  // dims 128..255: army-head input -> LDS as fp8
      unsigned o0 = (unsigned)__builtin_amdgcn_cvt_pk_fp8_f32(h[0], h[1], 0, false);
      o0 = (unsigned)__builtin_amdgcn_cvt_pk_fp8_f32(h[2], h[3], (int)o0, true);
      unsigned o1 = (unsigned)__builtin_amdgcn_cvt_pk_fp8_f32(h[4], h[5], 0, false);
      o1 = (unsigned)__builtin_amdgcn_cvt_pk_fp8_f32(h[6], h[7], (int)o1, true);
      *(uint2*)&ha8[el * LDP8 + (j0 - 128)] = make_uint2(o0, o1);
    }
  }
  __syncthreads();

  // phase 2: army logits via fp8 MFMA. Wave w: edges w*16..w*16+15.
  const int w = t >> 6, l = t & 63;
  const int lr = l & 15, quad = l >> 4;
  floatx4 acc[4];
  for (int nt = 0; nt < 4; ++nt) acc[nt] = (floatx4){0.f, 0.f, 0.f, 0.f};
  for (int ks = 0; ks < 4; ++ks) {
    LLU av;
    av.u2 = *(const uint2*)&ha8[(w * 16 + lr) * LDP8 + ks * 32 + quad * 8];
#pragma unroll
    for (int nt = 0; nt < 4; ++nt) {
      LLU bv;
      bv.u2 = *(const uint2*)&a2t8[(nt * 16 + lr) * LDP8 + ks * 32 + quad * 8];
      acc[nt] = __builtin_amdgcn_mfma_f32_16x16x32_fp8_fp8(av.ll, bv.ll, acc[nt], 0, 0, 0);
    }
  }
#pragma unroll
  for (int nt = 0; nt < 4; ++nt) {
    int col = nt * 16 + lr;
    float bias = s_ab2[col];
#pragma unroll
    for (int r = 0; r < 4; ++r) {
      int el = w * 16 + quad * 4 + r;
      if (e0 + el >= E) continue;
      int sa = s_army[el];
      float v = acc[nt][r] + bias;
      v = (col < sa) ? v : -1e9f;  // col <= max_sendable = sa-1
      out_army[(size_t)(e0 + el) * 64 + col] = v;
    }
  }
}

extern "C" void kernel_launch(void* const* d_in, const int* in_sizes, int n_in,
                              void* d_out, int out_size, void* d_ws, size_t ws_size,
                              hipStream_t stream) {
  const float* emb_f = (const float*)d_in[0];
  const int* edges   = (const int*)d_in[1];
  const int* army    = (const int*)d_in[2];
  const float* W1    = (const float*)d_in[3];
  const float* b1    = (const float*)d_in[4];
  const float* W2    = (const float*)d_in[5];
  const float* b2    = (const float*)d_in[6];
  const float* A1    = (const float*)d_in[7];
  const float* ab1   = (const float*)d_in[8];
  const float* A2    = (const float*)d_in[9];
  const float* ab2   = (const float*)d_in[10];

  const int N = in_sizes[0] / 128;  // 100000 nodes
  const int E = in_sizes[1] / 2;    // 1000000 edges

  // workspace layout (all 16B-aligned)
  char* ws = (char*)d_ws;
  unsigned short* emb_bf = (unsigned short*)ws;                       // N*128 bf16
  unsigned short* WcatT  = (unsigned short*)(ws + (size_t)N * 256);   // 512*128 bf16
  unsigned char*  A2T8   = (unsigned char*)(WcatT + 512 * 128);       // 64*128 fp8
  unsigned char*  P8     = A2T8 + 64 * 128;                           // N*512 fp8

  float* out_edge = (float*)d_out;  // fp32 outputs
  float* out_army = out_edge + E;

  int n4 = (N * 128) / 4;
  hipLaunchKernelGGL(k_convert_emb, dim3((n4 + 255) / 256), dim3(256), 0, stream,
                     emb_f, emb_bf, n4);
  hipLaunchKernelGGL(k_prep_weights, dim3((512 * 128 + 64 * 128 + 255) / 256), dim3(256),
                     0, stream, W1, A1, A2, WcatT, A2T8);
  hipLaunchKernelGGL(k_precompute, dim3(((N + 63) / 64) * 4), dim3(256), 0, stream,
                     emb_bf, WcatT, P8, N);
  hipLaunchKernelGGL(k_edges, dim3((E + 63) / 64), dim3(256), 0, stream,
                     P8, A2T8, edges, army, b1, ab1, W2, b2, ab2,
                     out_edge, out_army, E);
}